// Round 3
// baseline (58.094 us; speedup 1.0000x reference)
//
#include <hip/hip_runtime.h>

// GaussianAntecedent: out[n,r] = mem[n,r] / (sum_r mem[n,r] + 1e-8)
// mem = exp2( -sum_d min( (q*x + pn)^2 , -L ) ),
//   q = sqrt(0.5*log2 e)/(sigma+eps), pn = -c*q, L = log2(1e-8)
//
// lane = rule (R=64 == wavefront). Per-lane constants in VGPRs.
// Latency attack (R2 was latency-bound: VALUBusy 37%, occ 29%, HBM 8%):
//  - 2 rows in flight per wave: independent acc/exp2/butterfly chains overlap
//  - explicit prefetch of next row-pair between compute and epilogue
//  - ROWS_PER_WAVE=8 -> 12500 waves keeps all SIMDs oversubscribed

typedef float v2f __attribute__((ext_vector_type(2)));

constexpr int DDIM = 32;
constexpr int RR   = 64;
constexpr int ROWS_PER_WAVE = 8;
constexpr int WPB  = 4;   // waves per block

__device__ inline float fast_exp2(float x) {
#if __has_builtin(__builtin_amdgcn_exp2f)
    return __builtin_amdgcn_exp2f(x);
#else
    return exp2f(x);
#endif
}

__global__ __launch_bounds__(256, 4) void gauss_antecedent_kernel(
    const float* __restrict__ X,
    const float* __restrict__ centers,
    const float* __restrict__ sigma,
    float* __restrict__ out, int N)
{
    const int lane = threadIdx.x & 63;
    const int wid  = blockIdx.x * WPB + (threadIdx.x >> 6);
    const int row0 = wid * ROWS_PER_WAVE;
    if (row0 >= N) return;

    const float SQK  = 0.84932180028801907f;  // sqrt(0.5 * log2(e))
    const float NEGL = 26.575424759098897f;   // -log2(1e-8)

    v2f q2[DDIM / 2], pn2[DDIM / 2];
    #pragma unroll
    for (int d = 0; d < DDIM; d += 4) {
        float4 cc = *reinterpret_cast<const float4*>(&centers[lane * DDIM + d]);
        float4 ss = *reinterpret_cast<const float4*>(&sigma[lane * DDIM + d]);
        float qa = SQK / (ss.x + 1e-8f);
        float qb = SQK / (ss.y + 1e-8f);
        float qc = SQK / (ss.z + 1e-8f);
        float qd = SQK / (ss.w + 1e-8f);
        q2[d / 2 + 0] = (v2f){qa, qb};
        q2[d / 2 + 1] = (v2f){qc, qd};
        pn2[d / 2 + 0] = (v2f){-cc.x * qa, -cc.y * qb};
        pn2[d / 2 + 1] = (v2f){-cc.z * qc, -cc.w * qd};
    }
    const v2f negl2 = {NEGL, NEGL};

    if (row0 + ROWS_PER_WAVE <= N) {
        // ---- fast path: full 8 rows, processed as 4 pairs ----
        const float4* __restrict__ xr =
            reinterpret_cast<const float4*>(X + (size_t)row0 * DDIM);
        float4 xa[8], xb[8];
        #pragma unroll
        for (int j = 0; j < 8; ++j) { xa[j] = xr[j]; xb[j] = xr[8 + j]; }

        #pragma unroll
        for (int i = 0; i < ROWS_PER_WAVE / 2; ++i) {
            v2f acca[2] = {{0.f,0.f},{0.f,0.f}};
            v2f accb[2] = {{0.f,0.f},{0.f,0.f}};
            #pragma unroll
            for (int j = 0; j < 8; ++j) {
                v2f a0 = {xa[j].x, xa[j].y}, a1 = {xa[j].z, xa[j].w};
                v2f b0 = {xb[j].x, xb[j].y}, b1 = {xb[j].z, xb[j].w};
                v2f ta0 = __builtin_elementwise_fma(q2[2*j],   a0, pn2[2*j]);
                v2f ta1 = __builtin_elementwise_fma(q2[2*j+1], a1, pn2[2*j+1]);
                v2f tb0 = __builtin_elementwise_fma(q2[2*j],   b0, pn2[2*j]);
                v2f tb1 = __builtin_elementwise_fma(q2[2*j+1], b1, pn2[2*j+1]);
                acca[0] += __builtin_elementwise_min(ta0 * ta0, negl2);
                acca[1] += __builtin_elementwise_min(ta1 * ta1, negl2);
                accb[0] += __builtin_elementwise_min(tb0 * tb0, negl2);
                accb[1] += __builtin_elementwise_min(tb1 * tb1, negl2);
            }
            // prefetch next pair before the long-latency epilogue
            if (i < ROWS_PER_WAVE / 2 - 1) {
                const float4* __restrict__ xn = reinterpret_cast<const float4*>(
                    X + (size_t)(row0 + 2 * (i + 1)) * DDIM);
                #pragma unroll
                for (int j = 0; j < 8; ++j) { xa[j] = xn[j]; xb[j] = xn[8 + j]; }
            }
            v2f ava = acca[0] + acca[1];
            v2f avb = accb[0] + accb[1];
            float ma = fast_exp2(-(ava.x + ava.y));
            float mb = fast_exp2(-(avb.x + avb.y));
            float Sa = ma, Sb = mb;
            #pragma unroll
            for (int k = 32; k >= 1; k >>= 1) {
                Sa += __shfl_xor(Sa, k, 64);
                Sb += __shfl_xor(Sb, k, 64);
            }
            const size_t o = (size_t)(row0 + 2 * i) * RR + lane;
            out[o]      = ma * __builtin_amdgcn_rcpf(Sa + 1e-8f);
            out[o + RR] = mb * __builtin_amdgcn_rcpf(Sb + 1e-8f);
        }
    } else {
        // ---- tail path (not taken for N=100000, kept for correctness) ----
        for (int n = row0; n < N; ++n) {
            const float4* __restrict__ xr =
                reinterpret_cast<const float4*>(X + (size_t)n * DDIM);
            v2f acc[2] = {{0.f,0.f},{0.f,0.f}};
            #pragma unroll
            for (int j = 0; j < 8; ++j) {
                float4 xj = xr[j];
                v2f a0 = {xj.x, xj.y}, a1 = {xj.z, xj.w};
                v2f t0 = __builtin_elementwise_fma(q2[2*j],   a0, pn2[2*j]);
                v2f t1 = __builtin_elementwise_fma(q2[2*j+1], a1, pn2[2*j+1]);
                acc[0] += __builtin_elementwise_min(t0 * t0, negl2);
                acc[1] += __builtin_elementwise_min(t1 * t1, negl2);
            }
            v2f av = acc[0] + acc[1];
            float mem = fast_exp2(-(av.x + av.y));
            float S = mem;
            #pragma unroll
            for (int k = 32; k >= 1; k >>= 1) S += __shfl_xor(S, k, 64);
            out[(size_t)n * RR + lane] = mem * __builtin_amdgcn_rcpf(S + 1e-8f);
        }
    }
}

extern "C" void kernel_launch(void* const* d_in, const int* in_sizes, int n_in,
                              void* d_out, int out_size, void* d_ws, size_t ws_size,
                              hipStream_t stream) {
    const float* X       = (const float*)d_in[0];
    const float* centers = (const float*)d_in[1];
    const float* sigma   = (const float*)d_in[2];
    float* out = (float*)d_out;

    const int N = in_sizes[0] / DDIM;  // 100000
    const int nwaves = (N + ROWS_PER_WAVE - 1) / ROWS_PER_WAVE;
    const int grid = (nwaves + WPB - 1) / WPB;

    gauss_antecedent_kernel<<<grid, 256, 0, stream>>>(X, centers, sigma, out, N);
}

// Round 5
// 37.028 us; speedup vs baseline: 1.5689x; 1.5689x over previous
//
#include <hip/hip_runtime.h>

// GaussianAntecedent: out[n,r] = mem[n,r] / (sum_r mem[n,r] + 1e-8)
// mem = exp2( -sum_d min( (q*x + pn)^2 , -L ) ),
//   q = sqrt(0.5*log2 e)/(sigma+eps), pn = -c*q, L = log2(1e-8)
//
// lane = rule (R=64 == wavefront). Per-lane constants in VGPRs.
// R3 post-mortem: serial-latency-bound; dominant stall was the 6-deep
// __shfl_xor chain (ds_swizzle/ds_bpermute = LDS pipe, ~60cy each).
// R5: DPP reduction (VALU pipe, ~2-4cy/step), ctrl as TEMPLATE param
// (builtin requires immediate): row_shr:1,2,4,8 + row_bcast:15 +
// row_bcast:31 -> total in lane 63 -> v_readlane broadcast (SGPR).
// 2 rows interleaved so the two DPP chains overlap.

typedef float v2f __attribute__((ext_vector_type(2)));

constexpr int DDIM = 32;
constexpr int RR   = 64;
constexpr int RPW  = 16;  // rows per wave (N=100000 -> 6250 waves, no tail)
constexpr int WPB  = 4;   // waves per block

__device__ inline float fast_exp2(float x) {
#if __has_builtin(__builtin_amdgcn_exp2f)
    return __builtin_amdgcn_exp2f(x);
#else
    return exp2f(x);
#endif
}

template <int CTRL>
__device__ inline float dpp_add(float x) {
    int t = __builtin_amdgcn_update_dpp(0, __float_as_int(x), CTRL, 0xF, 0xF, true);
    return x + __int_as_float(t);
}

// Wave64 sum, result broadcast to all lanes via SGPR.
__device__ inline float wave_sum_bcast(float x) {
    x = dpp_add<0x111>(x);  // row_shr:1
    x = dpp_add<0x112>(x);  // row_shr:2
    x = dpp_add<0x114>(x);  // row_shr:4
    x = dpp_add<0x118>(x);  // row_shr:8
    x = dpp_add<0x142>(x);  // row_bcast:15
    x = dpp_add<0x143>(x);  // row_bcast:31
    return __int_as_float(__builtin_amdgcn_readlane(__float_as_int(x), 63));
}

__global__ __launch_bounds__(256, 4) void gauss_antecedent_kernel(
    const float* __restrict__ X,
    const float* __restrict__ centers,
    const float* __restrict__ sigma,
    float* __restrict__ out, int N)
{
    const int lane = threadIdx.x & 63;
    const int wid  = blockIdx.x * WPB + (threadIdx.x >> 6);
    const int row0 = wid * RPW;
    if (row0 >= N) return;

    const float SQK  = 0.84932180028801907f;  // sqrt(0.5 * log2(e))
    const float NEGL = 26.575424759098897f;   // -log2(1e-8)

    // Per-lane (rule = lane) constants, held in VGPR pairs.
    v2f q2[DDIM / 2], pn2[DDIM / 2];
    #pragma unroll
    for (int d = 0; d < DDIM; d += 4) {
        float4 cc = *reinterpret_cast<const float4*>(&centers[lane * DDIM + d]);
        float4 ss = *reinterpret_cast<const float4*>(&sigma[lane * DDIM + d]);
        float qa = SQK / (ss.x + 1e-8f);
        float qb = SQK / (ss.y + 1e-8f);
        float qc = SQK / (ss.z + 1e-8f);
        float qd = SQK / (ss.w + 1e-8f);
        q2[d / 2 + 0] = (v2f){qa, qb};
        q2[d / 2 + 1] = (v2f){qc, qd};
        pn2[d / 2 + 0] = (v2f){-cc.x * qa, -cc.y * qb};
        pn2[d / 2 + 1] = (v2f){-cc.z * qc, -cc.w * qd};
    }
    const v2f negl2 = {NEGL, NEGL};

    if (row0 + RPW <= N) {
        // ---- fast path: RPW rows as pairs; both reductions interleave ----
        #pragma unroll 2
        for (int i = 0; i < RPW; i += 2) {
            // wave-uniform row index -> scalar-load path for X
            const int na = __builtin_amdgcn_readfirstlane(row0 + i);
            const float4* __restrict__ xra =
                reinterpret_cast<const float4*>(X + (size_t)na * DDIM);
            const float4* __restrict__ xrb = xra + DDIM / 4;

            v2f acca[2] = {{0.f,0.f},{0.f,0.f}};
            v2f accb[2] = {{0.f,0.f},{0.f,0.f}};
            #pragma unroll
            for (int j = 0; j < 8; ++j) {
                float4 a = xra[j], b = xrb[j];
                v2f a0 = {a.x, a.y}, a1 = {a.z, a.w};
                v2f b0 = {b.x, b.y}, b1 = {b.z, b.w};
                v2f ta0 = __builtin_elementwise_fma(q2[2*j],   a0, pn2[2*j]);
                v2f ta1 = __builtin_elementwise_fma(q2[2*j+1], a1, pn2[2*j+1]);
                v2f tb0 = __builtin_elementwise_fma(q2[2*j],   b0, pn2[2*j]);
                v2f tb1 = __builtin_elementwise_fma(q2[2*j+1], b1, pn2[2*j+1]);
                acca[0] += __builtin_elementwise_min(ta0 * ta0, negl2);
                acca[1] += __builtin_elementwise_min(ta1 * ta1, negl2);
                accb[0] += __builtin_elementwise_min(tb0 * tb0, negl2);
                accb[1] += __builtin_elementwise_min(tb1 * tb1, negl2);
            }
            v2f ava = acca[0] + acca[1];
            v2f avb = accb[0] + accb[1];
            float ma = fast_exp2(-(ava.x + ava.y));
            float mb = fast_exp2(-(avb.x + avb.y));
            float Sa = wave_sum_bcast(ma);
            float Sb = wave_sum_bcast(mb);
            const size_t o = (size_t)na * RR + lane;
            out[o]      = ma * __builtin_amdgcn_rcpf(Sa + 1e-8f);
            out[o + RR] = mb * __builtin_amdgcn_rcpf(Sb + 1e-8f);
        }
    } else {
        // ---- tail path (not taken for N=100000) ----
        for (int n = row0; n < N; ++n) {
            const int ns = __builtin_amdgcn_readfirstlane(n);
            const float4* __restrict__ xr =
                reinterpret_cast<const float4*>(X + (size_t)ns * DDIM);
            v2f acc[2] = {{0.f,0.f},{0.f,0.f}};
            #pragma unroll
            for (int j = 0; j < 8; ++j) {
                float4 xj = xr[j];
                v2f a0 = {xj.x, xj.y}, a1 = {xj.z, xj.w};
                v2f t0 = __builtin_elementwise_fma(q2[2*j],   a0, pn2[2*j]);
                v2f t1 = __builtin_elementwise_fma(q2[2*j+1], a1, pn2[2*j+1]);
                acc[0] += __builtin_elementwise_min(t0 * t0, negl2);
                acc[1] += __builtin_elementwise_min(t1 * t1, negl2);
            }
            v2f av = acc[0] + acc[1];
            float mem = fast_exp2(-(av.x + av.y));
            float S = wave_sum_bcast(mem);
            out[(size_t)ns * RR + lane] = mem * __builtin_amdgcn_rcpf(S + 1e-8f);
        }
    }
}

extern "C" void kernel_launch(void* const* d_in, const int* in_sizes, int n_in,
                              void* d_out, int out_size, void* d_ws, size_t ws_size,
                              hipStream_t stream) {
    const float* X       = (const float*)d_in[0];
    const float* centers = (const float*)d_in[1];
    const float* sigma   = (const float*)d_in[2];
    float* out = (float*)d_out;

    const int N = in_sizes[0] / DDIM;  // 100000
    const int nwaves = (N + RPW - 1) / RPW;
    const int grid = (nwaves + WPB - 1) / WPB;

    gauss_antecedent_kernel<<<grid, 256, 0, stream>>>(X, centers, sigma, out, N);
}

// Round 6
// 35.464 us; speedup vs baseline: 1.6381x; 1.0441x over previous
//
#include <hip/hip_runtime.h>

// GaussianAntecedent: out[n,r] = mem[n,r] / (sum_r mem[n,r] + 1e-8)
// mem = exp2( sum_d max( -(q*x + pn)^2 , L ) ),
//   q = sqrt(0.5*log2 e)/(sigma+eps), pn = -c*q, L = log2(1e-8) < 0
//
// lane = rule (R=64 == wavefront). Per-lane constants in VGPRs.
// R5 post-mortem: DPP reduce fixed the epilogue (47->37us) but still
// latency-bound (VALU 42%, occ 27%): X loads at loop top are issued and
// immediately consumed. R6:
//  - depth-1 software pipeline: issue next pair's X loads between compute
//    and epilogue, so ~200-300cy load latency hides under the ~150cy
//    DPP/exp2/store epilogue + next compute.
//  - clamped accumulate via max-trick: B = max(fma(t,-t,B), B+L)
//    (one pk_fma + one pk_add + 2 scalar max per 2 dims; negation folded).

typedef float v2f __attribute__((ext_vector_type(2)));

constexpr int DDIM = 32;
constexpr int RR   = 64;
constexpr int RPW  = 16;  // rows per wave (N=100000 -> 6250 waves, no tail)
constexpr int WPB  = 4;   // waves per block

__device__ inline float fast_exp2(float x) {
#if __has_builtin(__builtin_amdgcn_exp2f)
    return __builtin_amdgcn_exp2f(x);
#else
    return exp2f(x);
#endif
}

template <int CTRL>
__device__ inline float dpp_add(float x) {
    int t = __builtin_amdgcn_update_dpp(0, __float_as_int(x), CTRL, 0xF, 0xF, true);
    return x + __int_as_float(t);
}

// Wave64 sum, result broadcast to all lanes via SGPR.
__device__ inline float wave_sum_bcast(float x) {
    x = dpp_add<0x111>(x);  // row_shr:1
    x = dpp_add<0x112>(x);  // row_shr:2
    x = dpp_add<0x114>(x);  // row_shr:4
    x = dpp_add<0x118>(x);  // row_shr:8
    x = dpp_add<0x142>(x);  // row_bcast:15
    x = dpp_add<0x143>(x);  // row_bcast:31
    return __int_as_float(__builtin_amdgcn_readlane(__float_as_int(x), 63));
}

__global__ __launch_bounds__(256, 4) void gauss_antecedent_kernel(
    const float* __restrict__ X,
    const float* __restrict__ centers,
    const float* __restrict__ sigma,
    float* __restrict__ out, int N)
{
    const int lane = threadIdx.x & 63;
    const int wid  = blockIdx.x * WPB + (threadIdx.x >> 6);
    const int row0 = wid * RPW;
    if (row0 >= N) return;

    const float SQK = 0.84932180028801907f;   // sqrt(0.5 * log2(e))
    const float LC  = -26.575424759098897f;   // log2(1e-8)

    // Per-lane (rule = lane) constants, held in VGPR pairs.
    v2f q2[DDIM / 2], pn2[DDIM / 2];
    #pragma unroll
    for (int d = 0; d < DDIM; d += 4) {
        float4 cc = *reinterpret_cast<const float4*>(&centers[lane * DDIM + d]);
        float4 ss = *reinterpret_cast<const float4*>(&sigma[lane * DDIM + d]);
        float qa = SQK / (ss.x + 1e-8f);
        float qb = SQK / (ss.y + 1e-8f);
        float qc = SQK / (ss.z + 1e-8f);
        float qd = SQK / (ss.w + 1e-8f);
        q2[d / 2 + 0] = (v2f){qa, qb};
        q2[d / 2 + 1] = (v2f){qc, qd};
        pn2[d / 2 + 0] = (v2f){-cc.x * qa, -cc.y * qb};
        pn2[d / 2 + 1] = (v2f){-cc.z * qc, -cc.w * qd};
    }
    const v2f L2 = {LC, LC};

    if (row0 + RPW <= N) {
        const int r0s = __builtin_amdgcn_readfirstlane(row0);
        const float4* __restrict__ xbase =
            reinterpret_cast<const float4*>(X + (size_t)r0s * DDIM);

        // prologue: load first pair of rows (16 x float4 = 2 rows)
        float4 cur[16];
        #pragma unroll
        for (int j = 0; j < 16; ++j) cur[j] = xbase[j];

        #pragma unroll
        for (int p = 0; p < RPW / 2; ++p) {
            // ---- compute: 2 rows, negative clamped log2-sums ----
            v2f Ba[2] = {{0.f, 0.f}, {0.f, 0.f}};
            v2f Bb[2] = {{0.f, 0.f}, {0.f, 0.f}};
            #pragma unroll
            for (int j = 0; j < 8; ++j) {
                float4 a = cur[j], b = cur[8 + j];
                v2f a0 = {a.x, a.y}, a1 = {a.z, a.w};
                v2f b0 = {b.x, b.y}, b1 = {b.z, b.w};
                v2f ta0 = __builtin_elementwise_fma(q2[2*j],   a0, pn2[2*j]);
                v2f ta1 = __builtin_elementwise_fma(q2[2*j+1], a1, pn2[2*j+1]);
                v2f tb0 = __builtin_elementwise_fma(q2[2*j],   b0, pn2[2*j]);
                v2f tb1 = __builtin_elementwise_fma(q2[2*j+1], b1, pn2[2*j+1]);
                // B = max(B - t*t, B + L)  (exact: B + max(-t^2, L))
                v2f ua0 = __builtin_elementwise_fma(ta0, -ta0, Ba[0]);
                v2f ua1 = __builtin_elementwise_fma(ta1, -ta1, Ba[1]);
                v2f ub0 = __builtin_elementwise_fma(tb0, -tb0, Bb[0]);
                v2f ub1 = __builtin_elementwise_fma(tb1, -tb1, Bb[1]);
                Ba[0] = __builtin_elementwise_max(ua0, Ba[0] + L2);
                Ba[1] = __builtin_elementwise_max(ua1, Ba[1] + L2);
                Bb[0] = __builtin_elementwise_max(ub0, Bb[0] + L2);
                Bb[1] = __builtin_elementwise_max(ub1, Bb[1] + L2);
            }

            // ---- prefetch next pair BEFORE the epilogue ----
            float4 nxt[16];
            if (p < RPW / 2 - 1) {
                const float4* __restrict__ nb = xbase + (p + 1) * 16;
                #pragma unroll
                for (int j = 0; j < 16; ++j) nxt[j] = nb[j];
            }

            // ---- epilogue: exp2, DPP wave-sum, normalize, store ----
            v2f sa = Ba[0] + Ba[1];
            v2f sb = Bb[0] + Bb[1];
            float ma = fast_exp2(sa.x + sa.y);
            float mb = fast_exp2(sb.x + sb.y);
            float Sa = wave_sum_bcast(ma);
            float Sb = wave_sum_bcast(mb);
            const size_t o = (size_t)(r0s + 2 * p) * RR + lane;
            out[o]      = ma * __builtin_amdgcn_rcpf(Sa + 1e-8f);
            out[o + RR] = mb * __builtin_amdgcn_rcpf(Sb + 1e-8f);

            if (p < RPW / 2 - 1) {
                #pragma unroll
                for (int j = 0; j < 16; ++j) cur[j] = nxt[j];
            }
        }
    } else {
        // ---- tail path (not taken for N=100000) ----
        for (int n = row0; n < N; ++n) {
            const int ns = __builtin_amdgcn_readfirstlane(n);
            const float4* __restrict__ xr =
                reinterpret_cast<const float4*>(X + (size_t)ns * DDIM);
            v2f B[2] = {{0.f, 0.f}, {0.f, 0.f}};
            #pragma unroll
            for (int j = 0; j < 8; ++j) {
                float4 xj = xr[j];
                v2f a0 = {xj.x, xj.y}, a1 = {xj.z, xj.w};
                v2f t0 = __builtin_elementwise_fma(q2[2*j],   a0, pn2[2*j]);
                v2f t1 = __builtin_elementwise_fma(q2[2*j+1], a1, pn2[2*j+1]);
                v2f u0 = __builtin_elementwise_fma(t0, -t0, B[0]);
                v2f u1 = __builtin_elementwise_fma(t1, -t1, B[1]);
                B[0] = __builtin_elementwise_max(u0, B[0] + L2);
                B[1] = __builtin_elementwise_max(u1, B[1] + L2);
            }
            v2f s = B[0] + B[1];
            float mem = fast_exp2(s.x + s.y);
            float S = wave_sum_bcast(mem);
            out[(size_t)ns * RR + lane] = mem * __builtin_amdgcn_rcpf(S + 1e-8f);
        }
    }
}

extern "C" void kernel_launch(void* const* d_in, const int* in_sizes, int n_in,
                              void* d_out, int out_size, void* d_ws, size_t ws_size,
                              hipStream_t stream) {
    const float* X       = (const float*)d_in[0];
    const float* centers = (const float*)d_in[1];
    const float* sigma   = (const float*)d_in[2];
    float* out = (float*)d_out;

    const int N = in_sizes[0] / DDIM;  // 100000
    const int nwaves = (N + RPW - 1) / RPW;
    const int grid = (nwaves + WPB - 1) / WPB;

    gauss_antecedent_kernel<<<grid, 256, 0, stream>>>(X, centers, sigma, out, N);
}